// Round 1
// baseline (823.292 us; speedup 1.0000x reference)
//
#include <hip/hip_runtime.h>
#include <hip/hip_cooperative_groups.h>

namespace cg = cooperative_groups;

#define SEQ     8192
#define DM      1024
#define DSTATE  16
#define DLAT    32
#define NB      64          // blocks in cooperative kernel
#define CH      128         // SEQ / NB timesteps per block
#define NT      256         // threads per block
#define MAXITERS 20

__device__ __forceinline__ float ld_agent(const float* p) {
    return __hip_atomic_load(p, __ATOMIC_RELAXED, __HIP_MEMORY_SCOPE_AGENT);
}
__device__ __forceinline__ void st_agent(float* p, float v) {
    __hip_atomic_store(p, v, __ATOMIC_RELAXED, __HIP_MEMORY_SCOPE_AGENT);
}
__device__ __forceinline__ float sigmoidf(float x) {
    return 1.0f / (1.0f + __expf(-x));
}

// ---------------- Kernel 1: embedding gather + iteration-invariant x-projections ----------------
// xlam[t][c] = x_t . Wlam[c, 32:] + blam[c]   (similarly xu; xf/xf2 use cols 16: of Wf/Wf2)
__global__ __launch_bounds__(256) void k1_embed_proj(
    const int* __restrict__ tokens, const float* __restrict__ emb,
    const float* __restrict__ Wf,  const float* __restrict__ bf,
    const float* __restrict__ Wf2, const float* __restrict__ bf2,
    const float* __restrict__ Wlam,const float* __restrict__ blam,
    const float* __restrict__ Wu,  const float* __restrict__ bu,
    float* __restrict__ xlam, float* __restrict__ xu,
    float* __restrict__ xf,   float* __restrict__ xf2)
{
    __shared__ float xs[8][DM];                 // 32 KB: 8 token rows
    const int tid = threadIdx.x;
    const int tokbase = blockIdx.x * 8;

    for (int i = tid; i < 8 * (DM / 4); i += 256) {
        const int tok = i >> 8;                 // 256 float4 per row
        const int off = (i & 255) * 4;
        const int row = tokens[tokbase + tok];
        *reinterpret_cast<float4*>(&xs[tok][off]) =
            *reinterpret_cast<const float4*>(emb + (size_t)row * DM + off);
    }
    __syncthreads();

    #pragma unroll
    for (int rep = 0; rep < 2; ++rep) {
        const int idx = tid + rep * 256;        // 512 outputs per block
        const int tok = idx >> 6;
        const int o   = idx & 63;
        const int arr = o >> 4;
        const int c   = o & 15;
        const float* wrow;
        float bias;
        float* dst;
        if (arr == 0)      { wrow = Wlam + c * 1056 + 32; bias = blam[c]; dst = xlam; }
        else if (arr == 1) { wrow = Wu   + c * 1056 + 32; bias = bu[c];   dst = xu;   }
        else if (arr == 2) { wrow = Wf   + c * 1040 + 16; bias = bf[c];   dst = xf;   }
        else               { wrow = Wf2  + c * 1040 + 16; bias = bf2[c];  dst = xf2;  }
        float acc = 0.0f;
        for (int k = 0; k < DM; k += 4) {
            const float4 w = *reinterpret_cast<const float4*>(wrow + k);
            const float4 x = *reinterpret_cast<const float4*>(&xs[tok][k]);
            acc += w.x * x.x;
            acc += w.y * x.y;
            acc += w.z * x.z;
            acc += w.w * x.w;
        }
        dst[(size_t)(tokbase + tok) * 16 + c] = acc + bias;
    }
}

// ---------------- Kernel 2: cooperative fixed-point loop ----------------
// State z kept in LDS. 21 rounds: rounds 1..20 = reference iterations, round 21 = final h_star scan.
// Per round: z-proj -> local scan -> publish (A,B,sq) -> grid.sync -> cross-block prefix + done check
//            -> h apply -> (f_theta z-update | final write).
__global__ __launch_bounds__(256, 1) void k2_fixed_point(
    const float* __restrict__ Wf,  const float* __restrict__ Wf2,
    const float* __restrict__ Wlam,const float* __restrict__ Wu,
    const float* __restrict__ xf,  const float* __restrict__ xf2,
    const float* __restrict__ xlam,const float* __restrict__ xu,
    float* __restrict__ zg, float* __restrict__ hg, float* __restrict__ pubf)
{
    __shared__ float zs[CH][DLAT + 1];          // z chunk (padded, conflict-free)
    __shared__ float lam[CH][DSTATE + 1];       // lam, later reused for alpha
    __shared__ float uu [CH][DSTATE + 1];       // u,   later reused for sigma
    __shared__ float hh [CH][DSTATE + 1];       // h chunk
    __shared__ float wlamz[16][32], wuz[16][32];// z-part weights
    __shared__ float wfh[16][16], wf2h[16][16]; // h-part weights
    __shared__ float segA[16][17], segB[16][17];
    __shared__ float segPa[16][17], segPb[16][17];
    __shared__ float grpA[16][5], grpB[16][5];
    __shared__ float hp0[16];                   // h at (chunk start - 1)
    __shared__ float blockA[16], blockB[16];
    __shared__ float red[4];
    __shared__ float sq_lds;                    // this block's ||dz||^2 partial (prev round)
    __shared__ float sumsq_s;                   // global ||z_k - z_{k-1}||^2

    const int tid = threadIdx.x;
    const int b = blockIdx.x;
    const int tbase = b * CH;
    cg::grid_group grid = cg::this_grid();

    // one-time LDS init
    for (int i = tid; i < 16 * 32; i += NT) {
        wlamz[i >> 5][i & 31] = Wlam[(size_t)(i >> 5) * 1056 + (i & 31)];
        wuz  [i >> 5][i & 31] = Wu  [(size_t)(i >> 5) * 1056 + (i & 31)];
    }
    for (int i = tid; i < 16 * 16; i += NT) {
        wfh [i >> 4][i & 15] = Wf [(size_t)(i >> 4) * 1040 + (i & 15)];
        wf2h[i >> 4][i & 15] = Wf2[(size_t)(i >> 4) * 1040 + (i & 15)];
    }
    for (int i = tid; i < CH * DLAT; i += NT) zs[i >> 5][i & 31] = 0.0f;
    if (tid == 0) sq_lds = __builtin_inff();    // round-1 publish => never "done" at r=1
    __syncthreads();

    bool done = false;
    for (int r = 1; r <= MAXITERS + 1; ++r) {
        // ---- Phase A: lam, u from current z ----
        {
            const int t = tid & (CH - 1);
            const int grp = tid >> 7;           // 0..1 (wave-uniform)
            float zrow[DLAT];
            #pragma unroll
            for (int j = 0; j < DLAT; ++j) zrow[j] = zs[t][j];
            const size_t gidx = (size_t)(tbase + t) * 16 + grp * 8;
            const float4 la = *reinterpret_cast<const float4*>(xlam + gidx);
            const float4 lb = *reinterpret_cast<const float4*>(xlam + gidx + 4);
            const float4 ua = *reinterpret_cast<const float4*>(xu + gidx);
            const float4 ub = *reinterpret_cast<const float4*>(xu + gidx + 4);
            const float xlv[8] = {la.x, la.y, la.z, la.w, lb.x, lb.y, lb.z, lb.w};
            const float xuv[8] = {ua.x, ua.y, ua.z, ua.w, ub.x, ub.y, ub.z, ub.w};
            #pragma unroll
            for (int cc = 0; cc < 8; ++cc) {
                const int c = grp * 8 + cc;
                float al = xlv[cc], au = xuv[cc];
                #pragma unroll
                for (int j = 0; j < DLAT; ++j) {
                    al += zrow[j] * wlamz[c][j];
                    au += zrow[j] * wuz[c][j];
                }
                lam[t][c] = sigmoidf(al);
                uu[t][c] = au;
            }
        }
        __syncthreads();

        // ---- Phase B: block-local scan (h_t = lam_t*h_{t-1} + u_t as affine composition) ----
        float pa[8], pb[8];                     // per-step prefixes relative to segment start
        {
            const int c = tid & 15, seg = tid >> 4;   // 16 segs x 8 steps
            float Pa = 1.0f, Pb = 0.0f;
            #pragma unroll
            for (int i = 0; i < 8; ++i) {
                const int t = seg * 8 + i;
                const float a = lam[t][c], bb = uu[t][c];
                Pa = a * Pa;
                Pb = a * Pb + bb;
                pa[i] = Pa; pb[i] = Pb;
            }
            segA[c][seg] = Pa; segB[c][seg] = Pb;
        }
        __syncthreads();
        if (tid < 16) {                          // serial seg-compose, 16 steps
            const int c = tid;
            float Ea = 1.0f, Eb = 0.0f;
            #pragma unroll
            for (int s = 0; s < 16; ++s) {
                segPa[c][s] = Ea; segPb[c][s] = Eb;      // exclusive prefix
                const float Ta = segA[c][s], Tb = segB[c][s];
                Ea = Ta * Ea; Eb = Ta * Eb + Tb;
            }
            blockA[c] = Ea; blockB[c] = Eb;              // block total
        }
        __syncthreads();

        // ---- Phase C: publish (A, B, sq_prev) ----
        const int p = r & 1;
        {
            float* pub = pubf + ((size_t)(p * NB) + b) * 40;
            if (tid < 16)       st_agent(&pub[tid], blockA[tid]);
            else if (tid < 32)  st_agent(&pub[tid], blockB[tid - 16]);
            else if (tid == 32) st_agent(&pub[32], sq_lds);
        }
        grid.sync();

        // ---- Phase D: cross-block prefix + convergence check ----
        if (tid < 64) {
            const int c = tid & 15, g = tid >> 4;        // 4 groups of 16 predecessors
            float Ga = 1.0f, Gb = 0.0f;
            #pragma unroll
            for (int jj = 0; jj < 16; ++jj) {
                const int j = g * 16 + jj;
                const float* pj = pubf + ((size_t)(p * NB) + j) * 40;
                const bool use = (j < b);
                const float a  = use ? ld_agent(pj + c) : 1.0f;
                const float bb = use ? ld_agent(pj + 16 + c) : 0.0f;
                Ga = a * Ga; Gb = a * Gb + bb;
            }
            grpA[c][g] = Ga; grpB[c][g] = Gb;
            // global sum of squared-update norms (identical reduce in every block)
            float sv = ld_agent(pubf + ((size_t)(p * NB) + tid) * 40 + 32);
            #pragma unroll
            for (int off = 32; off >= 1; off >>= 1) sv += __shfl_xor(sv, off);
            if (tid == 0) sumsq_s = sv;
        }
        __syncthreads();
        if (tid < 16) {
            const int c = tid;
            float Pa = 1.0f, Pb = 0.0f;
            #pragma unroll
            for (int g = 0; g < 4; ++g) {
                const float a = grpA[c][g], bb = grpB[c][g];
                Pa = a * Pa; Pb = a * Pb + bb;
            }
            hp0[c] = Pb;                                  // h_{tbase-1} (h_{-1} = 0)
        }
        if (r >= 2 && sumsq_s < 1e-10f) done = true;      // norm(z_k - z_{k-1}) < 1e-5
        __syncthreads();

        // ---- Phase E: apply prefixes -> h chunk ----
        {
            const int c = tid & 15, seg = tid >> 4;
            const float base = segPa[c][seg] * hp0[c] + segPb[c][seg];
            #pragma unroll
            for (int i = 0; i < 8; ++i) hh[seg * 8 + i][c] = pa[i] * base + pb[i];
        }
        __syncthreads();

        if (r == MAXITERS + 1 || done) {
            // final: write z_star, h_star for the output kernel
            for (int i = tid; i < CH * DSTATE; i += NT) {
                const int t = i >> 4, c = i & 15;
                hg[(size_t)(tbase + t) * 16 + c] = hh[t][c];
            }
            for (int i = tid; i < CH * DLAT; i += NT) {
                const int t = i >> 5, j = i & 31;
                zg[(size_t)(tbase + t) * 32 + j] = zs[t][j];
            }
            break;                                        // uniform across all blocks
        }

        // ---- Phase F: f_theta ODE step ----
        const int t = tid & (CH - 1);
        const int half = tid >> 7;                        // wave-uniform
        {
            // alpha/sigma projections from h_prev
            float hp[16];
            const int tp = (t == 0) ? 0 : t - 1;
            #pragma unroll
            for (int j = 0; j < 16; ++j) hp[j] = (t == 0) ? hp0[j] : hh[tp][j];
            const size_t gidx = (size_t)(tbase + t) * 16 + half * 8;
            const float4 fa = *reinterpret_cast<const float4*>(xf + gidx);
            const float4 fb = *reinterpret_cast<const float4*>(xf + gidx + 4);
            const float4 ga = *reinterpret_cast<const float4*>(xf2 + gidx);
            const float4 gb = *reinterpret_cast<const float4*>(xf2 + gidx + 4);
            const float xfv[8] = {fa.x, fa.y, fa.z, fa.w, fb.x, fb.y, fb.z, fb.w};
            const float x2v[8] = {ga.x, ga.y, ga.z, ga.w, gb.x, gb.y, gb.z, gb.w};
            #pragma unroll
            for (int cc = 0; cc < 8; ++cc) {
                const int c = half * 8 + cc;
                float aa = xfv[cc], ss = x2v[cc];
                #pragma unroll
                for (int j = 0; j < 16; ++j) {
                    aa += hp[j] * wfh[c][j];
                    ss += hp[j] * wf2h[c][j];
                }
                lam[t][c] = sigmoidf(aa);                 // alpha (reuse LDS)
                uu[t][c]  = sigmoidf(ss);                 // sigma (reuse LDS)
            }
        }
        __syncthreads();

        float dz[16];
        float ssq = 0.0f;
        {
            float uv[16], vv[16], av[16], sg[16];
            #pragma unroll
            for (int c = 0; c < 16; ++c) {
                uv[c] = zs[t][c];
                vv[c] = zs[t][16 + c];
                av[c] = lam[t][c];
                sg[c] = uu[t][c];
            }
            #pragma unroll
            for (int c = 0; c < 16; ++c) {
                const float th = tanhf(30.0f * (vv[c] - uv[c]));
                float d;
                if (half == 0)
                    d =  1.0f - av[c] * __expf(15.6f * vv[c]) * (1.0f - 0.26f * (0.3f - uv[c])) + sg[c] * th;
                else
                    d = -1.0f + av[c] * __expf(15.6f * uv[c]) * (1.0f + 0.26f * (0.3f - vv[c])) + sg[c] * th;
                dz[c] = 0.001f * d;
                ssq += dz[c] * dz[c];
            }
        }
        __syncthreads();                                  // all z reads done before writes
        #pragma unroll
        for (int c = 0; c < 16; ++c) zs[t][half * 16 + c] += dz[c];

        // block-reduce ssq -> sq_lds for next round's publish
        #pragma unroll
        for (int off = 32; off >= 1; off >>= 1) ssq += __shfl_xor(ssq, off);
        if ((tid & 63) == 0) red[tid >> 6] = ssq;
        __syncthreads();
        if (tid == 0) sq_lds = red[0] + red[1] + red[2] + red[3];
        __syncthreads();
    }
}

// ---------------- Kernel 3: out = [z, h] @ Wout.T + bout ----------------
__global__ __launch_bounds__(256) void k3_out(
    const float* __restrict__ zg, const float* __restrict__ hg,
    const float* __restrict__ Wout, const float* __restrict__ bout,
    float* __restrict__ out)
{
    __shared__ float zh[48];
    const int t = blockIdx.x;
    const int tid = threadIdx.x;
    if (tid < 32)      zh[tid] = zg[(size_t)t * 32 + tid];
    else if (tid < 48) zh[tid] = hg[(size_t)t * 16 + (tid - 32)];
    __syncthreads();
    #pragma unroll
    for (int k = 0; k < 4; ++k) {
        const int m = tid + k * 256;
        const float* w = Wout + (size_t)m * 48;
        float acc = bout[m];
        #pragma unroll
        for (int j = 0; j < 48; j += 4) {
            const float4 w4 = *reinterpret_cast<const float4*>(w + j);
            acc += w4.x * zh[j];
            acc += w4.y * zh[j + 1];
            acc += w4.z * zh[j + 2];
            acc += w4.w * zh[j + 3];
        }
        out[(size_t)t * 1024 + m] = acc;
    }
}

extern "C" void kernel_launch(void* const* d_in, const int* in_sizes, int n_in,
                              void* d_out, int out_size, void* d_ws, size_t ws_size,
                              hipStream_t stream) {
    (void)in_sizes; (void)n_in; (void)out_size; (void)ws_size;
    const int*   tokens = (const int*)  d_in[0];
    const float* emb    = (const float*)d_in[1];
    const float* Wf     = (const float*)d_in[2];
    const float* bf     = (const float*)d_in[3];
    const float* Wf2    = (const float*)d_in[4];
    const float* bf2    = (const float*)d_in[5];
    const float* Wlam   = (const float*)d_in[6];
    const float* blam   = (const float*)d_in[7];
    const float* Wu     = (const float*)d_in[8];
    const float* bu     = (const float*)d_in[9];
    const float* Wout   = (const float*)d_in[10];
    const float* bout   = (const float*)d_in[11];

    float* ws   = (float*)d_ws;
    float* xlam = ws;                 // 8192*16
    float* xu   = ws + 131072;        // 8192*16
    float* xf   = ws + 262144;        // 8192*16
    float* xf2  = ws + 393216;        // 8192*16
    float* zg   = ws + 524288;        // 8192*32
    float* hg   = ws + 786432;        // 8192*16
    float* pubf = ws + 917504;        // 2*64*40 publish slots

    k1_embed_proj<<<SEQ / 8, 256, 0, stream>>>(tokens, emb, Wf, bf, Wf2, bf2,
                                               Wlam, blam, Wu, bu,
                                               xlam, xu, xf, xf2);

    void* kargs[] = { (void*)&Wf, (void*)&Wf2, (void*)&Wlam, (void*)&Wu,
                      (void*)&xf, (void*)&xf2, (void*)&xlam, (void*)&xu,
                      (void*)&zg, (void*)&hg, (void*)&pubf };
    hipLaunchCooperativeKernel(k2_fixed_point, dim3(NB), dim3(NT), kargs, 0, stream);

    k3_out<<<SEQ, 256, 0, stream>>>(zg, hg, Wout, bout, (float*)d_out);
}

// Round 2
// 371.078 us; speedup vs baseline: 2.2187x; 2.2187x over previous
//
#include <hip/hip_runtime.h>

#define SEQ     8192
#define DM      1024
#define DSTATE  16
#define DLAT    32
#define NB      64          // blocks in fixed-point kernel
#define CH      128         // SEQ / NB timesteps per block
#define NT      256         // threads per block
#define MAXITERS 20

__device__ __forceinline__ float ld_agent(const float* p) {
    return __hip_atomic_load(p, __ATOMIC_RELAXED, __HIP_MEMORY_SCOPE_AGENT);
}
__device__ __forceinline__ void st_agent(float* p, float v) {
    __hip_atomic_store(p, v, __ATOMIC_RELAXED, __HIP_MEMORY_SCOPE_AGENT);
}
__device__ __forceinline__ float sigmoidf(float x) {
    return 1.0f / (1.0f + __expf(-x));
}
// tanh(x) = 1 - 2/(e^{2x}+1); inf-safe (e->inf gives 1, e->0 gives -1)
__device__ __forceinline__ float tanh_fast(float x) {
    const float e = __expf(2.0f * x);
    return 1.0f - 2.0f / (e + 1.0f);
}

// ---------------- Kernel 1: embedding gather + iteration-invariant x-projections ----------------
// 512 blocks x 16 tokens. X tile in LDS (64 KB). thread = (out-row r in [0,64), token-quad tg in [0,4)):
// streams its weight row once (float4), FMAs into 4 token accumulators; x reads are wave-broadcast.
__global__ __launch_bounds__(256) void k1_embed_proj(
    const int* __restrict__ tokens, const float* __restrict__ emb,
    const float* __restrict__ Wf,  const float* __restrict__ bf,
    const float* __restrict__ Wf2, const float* __restrict__ bf2,
    const float* __restrict__ Wlam,const float* __restrict__ blam,
    const float* __restrict__ Wu,  const float* __restrict__ bu,
    float* __restrict__ xlam, float* __restrict__ xu,
    float* __restrict__ xf,   float* __restrict__ xf2,
    unsigned int* __restrict__ flags)
{
    __shared__ float xs[16][DM];                 // 64 KB
    const int tid = threadIdx.x;
    const int tokbase = blockIdx.x * 16;

    // reset k2's sync flags every launch (poison/replay safety)
    if (blockIdx.x == 0 && tid < 2 * NB) flags[tid] = 0u;

    for (int j = tid; j < 16 * 256; j += 256) {  // 4096 float4, coalesced per token row
        const int tok = j >> 8;
        const int q   = j & 255;
        const int row = tokens[tokbase + tok];
        *reinterpret_cast<float4*>(&xs[tok][q * 4]) =
            *reinterpret_cast<const float4*>(emb + (size_t)row * DM + q * 4);
    }
    __syncthreads();

    const int r  = tid & 63;                     // output row 0..63
    const int tg = tid >> 6;                     // token quad 0..3 (wave-uniform)
    const int c  = r & 15;
    const float* wrow;
    float bias;
    float* dst;
    if (r < 16)      { wrow = Wlam + c * 1056 + 32; bias = blam[c]; dst = xlam; }
    else if (r < 32) { wrow = Wu   + c * 1056 + 32; bias = bu[c];   dst = xu;   }
    else if (r < 48) { wrow = Wf   + c * 1040 + 16; bias = bf[c];   dst = xf;   }
    else             { wrow = Wf2  + c * 1040 + 16; bias = bf2[c];  dst = xf2;  }

    float a0 = 0.f, a1 = 0.f, a2 = 0.f, a3 = 0.f;
    const int t0 = tg * 4;
    for (int k = 0; k < DM; k += 4) {
        const float4 w  = *reinterpret_cast<const float4*>(wrow + k);
        const float4 x0 = *reinterpret_cast<const float4*>(&xs[t0 + 0][k]);
        const float4 x1 = *reinterpret_cast<const float4*>(&xs[t0 + 1][k]);
        const float4 x2 = *reinterpret_cast<const float4*>(&xs[t0 + 2][k]);
        const float4 x3 = *reinterpret_cast<const float4*>(&xs[t0 + 3][k]);
        a0 += w.x * x0.x + w.y * x0.y + w.z * x0.z + w.w * x0.w;
        a1 += w.x * x1.x + w.y * x1.y + w.z * x1.z + w.w * x1.w;
        a2 += w.x * x2.x + w.y * x2.y + w.z * x2.z + w.w * x2.w;
        a3 += w.x * x3.x + w.y * x3.y + w.z * x3.z + w.w * x3.w;
    }
    dst[(size_t)(tokbase + t0 + 0) * 16 + c] = a0 + bias;
    dst[(size_t)(tokbase + t0 + 1) * 16 + c] = a1 + bias;
    dst[(size_t)(tokbase + t0 + 2) * 16 + c] = a2 + bias;
    dst[(size_t)(tokbase + t0 + 3) * 16 + c] = a3 + bias;
}

// ---------------- Kernel 2: fixed-point loop with flag-based cross-block sync ----------------
__global__ __launch_bounds__(256, 1) void k2_fixed_point(
    const float* __restrict__ Wf,  const float* __restrict__ Wf2,
    const float* __restrict__ Wlam,const float* __restrict__ Wu,
    const float* __restrict__ xf,  const float* __restrict__ xf2,
    const float* __restrict__ xlam,const float* __restrict__ xu,
    float* __restrict__ zg, float* __restrict__ hg,
    float* __restrict__ pubd, unsigned int* __restrict__ flags)
{
    __shared__ float zs[CH][DLAT + 1];
    __shared__ float lam[CH][DSTATE + 1];       // lam, later alpha
    __shared__ float uu [CH][DSTATE + 1];       // u,   later sigma
    __shared__ float hh [CH][DSTATE + 1];
    __shared__ float wlamz[16][32], wuz[16][32];
    __shared__ float wfh[16][16], wf2h[16][16];
    __shared__ float segA[16][17], segB[16][17];
    __shared__ float segPa[16][17], segPb[16][17];
    __shared__ float grpA[16][5], grpB[16][5];
    __shared__ float hp0[16];
    __shared__ float blockA[16], blockB[16];
    __shared__ float red[4];
    __shared__ float sq_lds;
    __shared__ float sumsq_s;

    const int tid = threadIdx.x;
    const int b = blockIdx.x;
    const int tbase = b * CH;

    for (int i = tid; i < 16 * 32; i += NT) {
        wlamz[i >> 5][i & 31] = Wlam[(size_t)(i >> 5) * 1056 + (i & 31)];
        wuz  [i >> 5][i & 31] = Wu  [(size_t)(i >> 5) * 1056 + (i & 31)];
    }
    for (int i = tid; i < 16 * 16; i += NT) {
        wfh [i >> 4][i & 15] = Wf [(size_t)(i >> 4) * 1040 + (i & 15)];
        wf2h[i >> 4][i & 15] = Wf2[(size_t)(i >> 4) * 1040 + (i & 15)];
    }
    for (int i = tid; i < CH * DLAT; i += NT) zs[i >> 5][i & 31] = 0.0f;
    if (tid == 0) sq_lds = __builtin_inff();

    // hoist iteration-invariant per-thread inputs into registers
    const int t    = tid & (CH - 1);
    const int half = tid >> 7;                  // wave-uniform
    float xlv[8], xuv[8], xfv[8], x2v[8];
    {
        const size_t gidx = (size_t)(tbase + t) * 16 + half * 8;
        const float4 la = *reinterpret_cast<const float4*>(xlam + gidx);
        const float4 lb = *reinterpret_cast<const float4*>(xlam + gidx + 4);
        const float4 ua = *reinterpret_cast<const float4*>(xu + gidx);
        const float4 ub = *reinterpret_cast<const float4*>(xu + gidx + 4);
        const float4 fa = *reinterpret_cast<const float4*>(xf + gidx);
        const float4 fb = *reinterpret_cast<const float4*>(xf + gidx + 4);
        const float4 ga = *reinterpret_cast<const float4*>(xf2 + gidx);
        const float4 gb = *reinterpret_cast<const float4*>(xf2 + gidx + 4);
        xlv[0]=la.x; xlv[1]=la.y; xlv[2]=la.z; xlv[3]=la.w; xlv[4]=lb.x; xlv[5]=lb.y; xlv[6]=lb.z; xlv[7]=lb.w;
        xuv[0]=ua.x; xuv[1]=ua.y; xuv[2]=ua.z; xuv[3]=ua.w; xuv[4]=ub.x; xuv[5]=ub.y; xuv[6]=ub.z; xuv[7]=ub.w;
        xfv[0]=fa.x; xfv[1]=fa.y; xfv[2]=fa.z; xfv[3]=fa.w; xfv[4]=fb.x; xfv[5]=fb.y; xfv[6]=fb.z; xfv[7]=fb.w;
        x2v[0]=ga.x; x2v[1]=ga.y; x2v[2]=ga.z; x2v[3]=ga.w; x2v[4]=gb.x; x2v[5]=gb.y; x2v[6]=gb.z; x2v[7]=gb.w;
    }
    __syncthreads();

    bool done = false;
    for (int r = 1; r <= MAXITERS + 1; ++r) {
        // ---- Phase A: lam, u from current z ----
        {
            float zrow[DLAT];
            #pragma unroll
            for (int j = 0; j < DLAT; ++j) zrow[j] = zs[t][j];
            #pragma unroll
            for (int cc = 0; cc < 8; ++cc) {
                const int c = half * 8 + cc;
                float al = xlv[cc], au = xuv[cc];
                #pragma unroll
                for (int j = 0; j < DLAT; ++j) {
                    al += zrow[j] * wlamz[c][j];
                    au += zrow[j] * wuz[c][j];
                }
                lam[t][c] = sigmoidf(al);
                uu[t][c] = au;
            }
        }
        __syncthreads();

        // ---- Phase B: block-local scan ----
        float pa[8], pb[8];
        {
            const int c = tid & 15, seg = tid >> 4;
            float Pa = 1.0f, Pb = 0.0f;
            #pragma unroll
            for (int i = 0; i < 8; ++i) {
                const int tt = seg * 8 + i;
                const float a = lam[tt][c], bb = uu[tt][c];
                Pa = a * Pa;
                Pb = a * Pb + bb;
                pa[i] = Pa; pb[i] = Pb;
            }
            segA[c][seg] = Pa; segB[c][seg] = Pb;
        }
        __syncthreads();
        if (tid < 16) {
            const int c = tid;
            float Ea = 1.0f, Eb = 0.0f;
            #pragma unroll
            for (int s = 0; s < 16; ++s) {
                segPa[c][s] = Ea; segPb[c][s] = Eb;
                const float Ta = segA[c][s], Tb = segB[c][s];
                Ea = Ta * Ea; Eb = Ta * Eb + Tb;
            }
            blockA[c] = Ea; blockB[c] = Eb;
        }
        __syncthreads();

        // ---- Phase C: publish (A, B, sq_prev), then release-tag flag with round ----
        const int p = r & 1;
        {
            float* pub = pubd + (((size_t)p * NB + b) << 6);
            if (tid < 16)       st_agent(&pub[tid], blockA[tid]);
            else if (tid < 32)  st_agent(&pub[tid], blockB[tid - 16]);
            else if (tid == 32) st_agent(&pub[32], sq_lds);
        }
        __syncthreads();                        // all waves' stores drained (vmcnt) at barrier
        if (tid == 0) {
            __threadfence();                    // agent-scope fence: data visible before flag
            __hip_atomic_store(&flags[p * NB + b], (unsigned int)r,
                               __ATOMIC_RELEASE, __HIP_MEMORY_SCOPE_AGENT);
        }

        // ---- spin: wait for all 64 blocks' round-r publications ----
        if (tid < NB) {
            const unsigned int* f = &flags[p * NB + tid];
            while (__hip_atomic_load(f, __ATOMIC_ACQUIRE, __HIP_MEMORY_SCOPE_AGENT)
                   < (unsigned int)r) {}
        }
        __syncthreads();

        // ---- Phase D: cross-block prefix + convergence check ----
        if (tid < 64) {
            const int c = tid & 15, g = tid >> 4;
            float Ga = 1.0f, Gb = 0.0f;
            #pragma unroll
            for (int jj = 0; jj < 16; ++jj) {
                const int j = g * 16 + jj;
                const float* pj = pubd + (((size_t)p * NB + j) << 6);
                const bool use = (j < b);
                const float a  = use ? ld_agent(pj + c) : 1.0f;
                const float bb = use ? ld_agent(pj + 16 + c) : 0.0f;
                Ga = a * Ga; Gb = a * Gb + bb;
            }
            grpA[c][g] = Ga; grpB[c][g] = Gb;
            float sv = ld_agent(pubd + (((size_t)p * NB + tid) << 6) + 32);
            #pragma unroll
            for (int off = 32; off >= 1; off >>= 1) sv += __shfl_xor(sv, off);
            if (tid == 0) sumsq_s = sv;
        }
        __syncthreads();
        if (tid < 16) {
            const int c = tid;
            float Pa = 1.0f, Pb = 0.0f;
            #pragma unroll
            for (int g = 0; g < 4; ++g) {
                const float a = grpA[c][g], bb = grpB[c][g];
                Pa = a * Pa; Pb = a * Pb + bb;
            }
            hp0[c] = Pb;
        }
        if (r >= 2 && sumsq_s < 1e-10f) done = true;
        __syncthreads();

        // ---- Phase E: apply prefixes -> h chunk ----
        {
            const int c = tid & 15, seg = tid >> 4;
            const float base = segPa[c][seg] * hp0[c] + segPb[c][seg];
            #pragma unroll
            for (int i = 0; i < 8; ++i) hh[seg * 8 + i][c] = pa[i] * base + pb[i];
        }
        __syncthreads();

        if (r == MAXITERS + 1 || done) {
            for (int i = tid; i < CH * DSTATE; i += NT) {
                const int tt = i >> 4, c = i & 15;
                hg[(size_t)(tbase + tt) * 16 + c] = hh[tt][c];
            }
            for (int i = tid; i < CH * DLAT; i += NT) {
                const int tt = i >> 5, j = i & 31;
                zg[(size_t)(tbase + tt) * 32 + j] = zs[tt][j];
            }
            break;                              // uniform across blocks (done is global)
        }

        // ---- Phase F: f_theta ODE step ----
        {
            float hp[16];
            const int tp = (t == 0) ? 0 : t - 1;
            #pragma unroll
            for (int j = 0; j < 16; ++j) hp[j] = (t == 0) ? hp0[j] : hh[tp][j];
            #pragma unroll
            for (int cc = 0; cc < 8; ++cc) {
                const int c = half * 8 + cc;
                float aa = xfv[cc], ss = x2v[cc];
                #pragma unroll
                for (int j = 0; j < 16; ++j) {
                    aa += hp[j] * wfh[c][j];
                    ss += hp[j] * wf2h[c][j];
                }
                lam[t][c] = sigmoidf(aa);       // alpha
                uu[t][c]  = sigmoidf(ss);       // sigma
            }
        }
        __syncthreads();

        float dz[16];
        float ssq = 0.0f;
        {
            #pragma unroll
            for (int c = 0; c < 16; ++c) {
                const float uv = zs[t][c];
                const float vv = zs[t][16 + c];
                const float av = lam[t][c];
                const float sg = uu[t][c];
                const float th = tanh_fast(30.0f * (vv - uv));
                float d;
                if (half == 0)
                    d =  1.0f - av * __expf(15.6f * vv) * (1.0f - 0.26f * (0.3f - uv)) + sg * th;
                else
                    d = -1.0f + av * __expf(15.6f * uv) * (1.0f + 0.26f * (0.3f - vv)) + sg * th;
                dz[c] = 0.001f * d;
                ssq += dz[c] * dz[c];
            }
        }
        __syncthreads();
        #pragma unroll
        for (int c = 0; c < 16; ++c) zs[t][half * 16 + c] += dz[c];

        #pragma unroll
        for (int off = 32; off >= 1; off >>= 1) ssq += __shfl_xor(ssq, off);
        if ((tid & 63) == 0) red[tid >> 6] = ssq;
        __syncthreads();
        if (tid == 0) sq_lds = red[0] + red[1] + red[2] + red[3];
        __syncthreads();
    }
}

// ---------------- Kernel 3: out = [z, h] @ Wout.T + bout ----------------
// 512 blocks x 16 tokens; weights register-resident (2 cols x 2 passes), zh broadcast from LDS.
__global__ __launch_bounds__(256) void k3_out(
    const float* __restrict__ zg, const float* __restrict__ hg,
    const float* __restrict__ Wout, const float* __restrict__ bout,
    float* __restrict__ out)
{
    __shared__ float zhs[16][48];
    const int tid = threadIdx.x;
    const int tb = blockIdx.x * 16;

    for (int i = tid; i < 16 * 48; i += 256) {
        const int tt = i / 48, j = i - tt * 48;
        zhs[tt][j] = (j < 32) ? zg[(size_t)(tb + tt) * 32 + j]
                              : hg[(size_t)(tb + tt) * 16 + (j - 32)];
    }
    __syncthreads();

    #pragma unroll
    for (int pass = 0; pass < 2; ++pass) {
        const int c0 = pass * 512 + tid;
        const int c1 = c0 + 256;
        float4 w0q[12], w1q[12];
        const float* w0 = Wout + (size_t)c0 * 48;
        const float* w1 = Wout + (size_t)c1 * 48;
        #pragma unroll
        for (int j = 0; j < 12; ++j) {
            w0q[j] = *reinterpret_cast<const float4*>(w0 + j * 4);
            w1q[j] = *reinterpret_cast<const float4*>(w1 + j * 4);
        }
        const float b0 = bout[c0], b1 = bout[c1];
        for (int tt = 0; tt < 16; ++tt) {
            float a0 = b0, a1 = b1;
            #pragma unroll
            for (int j = 0; j < 12; ++j) {
                const float4 z4 = *reinterpret_cast<const float4*>(&zhs[tt][j * 4]);
                a0 += w0q[j].x * z4.x + w0q[j].y * z4.y + w0q[j].z * z4.z + w0q[j].w * z4.w;
                a1 += w1q[j].x * z4.x + w1q[j].y * z4.y + w1q[j].z * z4.z + w1q[j].w * z4.w;
            }
            out[(size_t)(tb + tt) * 1024 + c0] = a0;
            out[(size_t)(tb + tt) * 1024 + c1] = a1;
        }
    }
}

extern "C" void kernel_launch(void* const* d_in, const int* in_sizes, int n_in,
                              void* d_out, int out_size, void* d_ws, size_t ws_size,
                              hipStream_t stream) {
    (void)in_sizes; (void)n_in; (void)out_size; (void)ws_size;
    const int*   tokens = (const int*)  d_in[0];
    const float* emb    = (const float*)d_in[1];
    const float* Wf     = (const float*)d_in[2];
    const float* bf     = (const float*)d_in[3];
    const float* Wf2    = (const float*)d_in[4];
    const float* bf2    = (const float*)d_in[5];
    const float* Wlam   = (const float*)d_in[6];
    const float* blam   = (const float*)d_in[7];
    const float* Wu     = (const float*)d_in[8];
    const float* bu     = (const float*)d_in[9];
    const float* Wout   = (const float*)d_in[10];
    const float* bout   = (const float*)d_in[11];

    float* ws   = (float*)d_ws;
    float* xlam = ws;                       // 131072 f
    float* xu   = ws + 131072;              // 131072 f
    float* xf   = ws + 262144;              // 131072 f
    float* xf2  = ws + 393216;              // 131072 f
    float* zg   = ws + 524288;              // 262144 f
    float* hg   = ws + 786432;              // 131072 f
    float* pubd = ws + 917504;              // 2*64*64 f = 8192 f
    unsigned int* flags = (unsigned int*)(ws + 925696);   // 128 u32

    k1_embed_proj<<<SEQ / 16, 256, 0, stream>>>(tokens, emb, Wf, bf, Wf2, bf2,
                                                Wlam, blam, Wu, bu,
                                                xlam, xu, xf, xf2, flags);

    void* kargs[] = { (void*)&Wf, (void*)&Wf2, (void*)&Wlam, (void*)&Wu,
                      (void*)&xf, (void*)&xf2, (void*)&xlam, (void*)&xu,
                      (void*)&zg, (void*)&hg, (void*)&pubd, (void*)&flags };
    hipLaunchCooperativeKernel(k2_fixed_point, dim3(NB), dim3(NT), kargs, 0, stream);

    k3_out<<<SEQ / 16, 256, 0, stream>>>(zg, hg, Wout, bout, (float*)d_out);
}